// Round 16
// baseline (303.727 us; speedup 1.0000x reference)
//
#include <hip/hip_runtime.h>
#include <hip/hip_bf16.h>

#define D 64
#define FP_SCALE 262144.0f          // 2^18 (order-free int accumulation)
#define FP_INV   (1.0f / 262144.0f)
#define NPC 64                      // nodes per chunk
#define ASTR 65                     // odd acc stride (ints)

__device__ __forceinline__ unsigned short f2bf(float f) {   // rtne f32->bf16
    unsigned int u = __float_as_uint(f);
    u += 0x7fffu + ((u >> 16) & 1u);
    return (unsigned short)(u >> 16);
}

// ---------- bucket-granularity CSR build (deterministic) ----------
// bucket = dst>>2 (4 nodes). The agg kernel extracts slot from the packed
// record, so edges only need CHUNK-level grouping; bucket order within a
// chunk is free. 25K counters: 4x less scan work than per-node (round 15),
// 32 edges/cursor contention (round 13's 256/cursor was the bad regime).
__global__ void hist_kernel(const int* __restrict__ dst, int* __restrict__ bktCnt, int E) {
    int e = blockIdx.x * blockDim.x + threadIdx.x;
    if (e < E) atomicAdd(&bktCnt[dst[e] >> 2], 1);
}

__global__ void part_kernel(const int* __restrict__ cnt, int* __restrict__ partial, int n) {
    __shared__ int ws4[4];
    int t = threadIdx.x, lane = t & 63, w = t >> 6;
    int i = blockIdx.x * 256 + t;
    int c = (i < n) ? cnt[i] : 0;
    #pragma unroll
    for (int off = 32; off > 0; off >>= 1) c += __shfl_down(c, off);
    if (lane == 0) ws4[w] = c;
    __syncthreads();
    if (t == 0) partial[blockIdx.x] = ws4[0] + ws4[1] + ws4[2] + ws4[3];
}

__global__ void scan_kernel(int* __restrict__ partial, int nb) {
    __shared__ int wsum[8];
    int t = threadIdx.x, lane = t & 63, w = t >> 6;
    int carry = 0;
    for (int base = 0; base < nb; base += 512) {
        int i = base + t;
        int v = (i < nb) ? partial[i] : 0;
        int incl = v;
        #pragma unroll
        for (int off = 1; off < 64; off <<= 1) {
            int x = __shfl_up(incl, off);
            if (lane >= off) incl += x;
        }
        if (lane == 63) wsum[w] = incl;
        __syncthreads();
        int wpre = 0;
        for (int j = 0; j < w; ++j) wpre += wsum[j];
        int tot = 0;
        for (int j = 0; j < 8; ++j) tot += wsum[j];
        if (i < nb) partial[i] = carry + wpre + incl - v;
        carry += tot;
        __syncthreads();
    }
}

// bucketStart[i] = exclusive prefix; cursor seeded; sentinel at [npad] = E.
__global__ void bstart_kernel(const int* __restrict__ cnt, const int* __restrict__ partial,
                              int* __restrict__ bucketStart, int* __restrict__ cursor, int npad) {
    __shared__ int ws4[4];
    int t = threadIdx.x, lane = t & 63, w = t >> 6;
    int i = blockIdx.x * 256 + t;
    int c = (i < npad) ? cnt[i] : 0;
    int incl = c;
    #pragma unroll
    for (int off = 1; off < 64; off <<= 1) {
        int x = __shfl_up(incl, off);
        if (lane >= off) incl += x;
    }
    if (lane == 63) ws4[w] = incl;
    __syncthreads();
    int wpre = 0;
    for (int j = 0; j < w; ++j) wpre += ws4[j];
    int st = partial[blockIdx.x] + wpre + incl - c;
    if (i < npad) {
        bucketStart[i] = st;
        cursor[i] = st;
        if (i == npad - 1) bucketStart[npad] = st + c;   // sentinel = E
    }
}

// Pack (w*2^18, src, slot=dst&63) into one uint64 per edge, bucket-bucketed.
// Within-bucket placement is atomic-order nondeterministic, but the
// aggregate's integer accumulation is order-free -> output is input-pure.
__global__ void fill_kernel(const int* __restrict__ src, const int* __restrict__ dst,
                            const float* __restrict__ ew, int* __restrict__ cursor,
                            unsigned long long* __restrict__ perm64, int E) {
    int e = blockIdx.x * blockDim.x + threadIdx.x;
    if (e < E) {
        int d = dst[e];
        int p = atomicAdd(&cursor[d >> 2], 1);
        unsigned lo = ((unsigned)src[e] << 6) | (unsigned)(d & (NPC - 1));
        perm64[p] = ((unsigned long long)__float_as_uint(ew[e] * FP_SCALE) << 32) | lo;
    }
}

// ---------- fused aggregate + linear + relu (round-12 proven mapping) ----------
// Block owns NPC=64 nodes -> chunk edge range [es,ee) (~512 edges).
// LDS swizzle (ASTR=65): feature f of slot s at word s*65 + (f&3)*16 + (f>>2).
// Edge mapping (round-12 measured-best): 64-edge superblocks, group slice = 4
// consecutive edges (batch-4), wave's groups 16 apart, bounds block-uniform.
// Wtb bf16 (FP_INV folded, exact pow2): LDS 25.1KB -> 6 blocks/CU.
// perm64 via nontemporal loads: streamed once, don't evict gather rows.
// ~8M bank-conflict cycles = LDS-atomic RMW floor (invariant across r12-r14).
template<bool IN_F32, bool OUT_BF>
__global__ void agg_fused_kernel(const void* __restrict__ xin,
                                 const unsigned long long* __restrict__ perm64,
                                 const int* __restrict__ bucketStart,
                                 const float* __restrict__ W,
                                 const float* __restrict__ bias,
                                 void* __restrict__ xout,
                                 int N) {
    __shared__ int acc[NPC * ASTR];        // 16.6 KB
    __shared__ unsigned short Wtb[D][D];   // 8.2 KB: bf16(W^T * FP_INV)
    __shared__ float bsh[D];
    int t = threadIdx.x;
    int bid = blockIdx.x;
    int nodeBase = bid * NPC;
    int nodeEnd = min(nodeBase + NPC, N);
    int es = bucketStart[bid * 16];
    int ee = bucketStart[(bid + 1) * 16];

    for (int i = t; i < NPC * ASTR / 4; i += 256)
        reinterpret_cast<int4*>(acc)[i] = make_int4(0, 0, 0, 0);
    for (int i = t; i < D * D; i += 256) {   // one-time transpose + bf16 pack
        int j = i >> 6, d = i & 63;
        Wtb[d][j] = f2bf(W[i] * FP_INV);     // *FP_INV exact (pow2 exponent shift)
    }
    if (t < D) bsh[t] = bias[t];
    __syncthreads();

    int g = t >> 4;               // group 0..15 (16 lanes)
    int i16 = t & 15;             // lane in group: features 4*i16..+3
    int gl = g & 3;               // position within wave
    int w4 = g >> 2;              // wave index

#define EDGE_ATOMIC(pk)                                                         \
    {                                                                           \
        unsigned lo_ = (unsigned)(pk);                                          \
        float w_ = __uint_as_float((unsigned)((pk) >> 32));                     \
        int slot_ = (int)(lo_ & (NPC - 1));                                     \
        int s_ = (int)(lo_ >> 6);                                               \
        float v0_, v1_, v2_, v3_;                                               \
        if (IN_F32) {                                                           \
            float4 u_ = *reinterpret_cast<const float4*>(                       \
                (const float*)xin + (size_t)s_ * D + (i16 << 2));               \
            v0_ = u_.x; v1_ = u_.y; v2_ = u_.z; v3_ = u_.w;                     \
        } else {                                                                \
            uint2 u_ = *reinterpret_cast<const uint2*>(                         \
                (const unsigned short*)xin + (size_t)s_ * D + (i16 << 2));      \
            v0_ = __uint_as_float(u_.x << 16);                                  \
            v1_ = __uint_as_float(u_.x & 0xffff0000u);                          \
            v2_ = __uint_as_float(u_.y << 16);                                  \
            v3_ = __uint_as_float(u_.y & 0xffff0000u);                          \
        }                                                                       \
        int base_ = slot_ * ASTR + i16;                                         \
        atomicAdd(&acc[base_ +  0], (int)(w_ * v0_));                           \
        atomicAdd(&acc[base_ + 16], (int)(w_ * v1_));                           \
        atomicAdd(&acc[base_ + 32], (int)(w_ * v2_));                           \
        atomicAdd(&acc[base_ + 48], (int)(w_ * v3_));                           \
    }

    // 64-edge superblocks: group slice = 4 consecutive edges (batch-4),
    // wave's 4 groups 16 apart; bounds uniform across block.
    int myOff = es + gl * 16 + w4 * 4;
    int cnt = ee - es;
    int kmax = cnt >> 6;
    for (int k = 0; k < kmax; ++k) {
        int e0 = myOff + (k << 6);
        unsigned long long pk0 = __builtin_nontemporal_load(&perm64[e0 + 0]);
        unsigned long long pk1 = __builtin_nontemporal_load(&perm64[e0 + 1]);
        unsigned long long pk2 = __builtin_nontemporal_load(&perm64[e0 + 2]);
        unsigned long long pk3 = __builtin_nontemporal_load(&perm64[e0 + 3]);
        EDGE_ATOMIC(pk0); EDGE_ATOMIC(pk1); EDGE_ATOMIC(pk2); EDGE_ATOMIC(pk3);
    }
    for (int e = es + (kmax << 6) + g; e < ee; e += 16) {   // tail
        unsigned long long pk = __builtin_nontemporal_load(&perm64[e]);
        EDGE_ATOMIC(pk);
    }
#undef EDGE_ATOMIC
    __syncthreads();

    // flush: wave owns 16 nodes; un-swizzle via broadcast reads; Wtb bf16
    int wave = t >> 6, lane = t & 63;
    int sBase = wave * 16;
    float o[16];
    #pragma unroll
    for (int i = 0; i < 16; ++i) o[i] = 0.f;
    for (int q = 0; q < 16; ++q) {
        float w0 = __uint_as_float((unsigned)Wtb[4 * q + 0][lane] << 16);
        float w1 = __uint_as_float((unsigned)Wtb[4 * q + 1][lane] << 16);
        float w2 = __uint_as_float((unsigned)Wtb[4 * q + 2][lane] << 16);
        float w3 = __uint_as_float((unsigned)Wtb[4 * q + 3][lane] << 16);
        #pragma unroll
        for (int i = 0; i < 16; ++i) {
            int base = (sBase + i) * ASTR + q;
            float a0 = (float)acc[base +  0];
            float a1 = (float)acc[base + 16];
            float a2 = (float)acc[base + 32];
            float a3 = (float)acc[base + 48];
            o[i] = fmaf(a0, w0, fmaf(a1, w1, fmaf(a2, w2, fmaf(a3, w3, o[i]))));
        }
    }
    #pragma unroll
    for (int i = 0; i < 16; ++i) {
        int node = nodeBase + sBase + i;
        if (node < nodeEnd) {
            float v = fmaxf(bsh[lane] + o[i], 0.0f);
            size_t off = (size_t)node * D + lane;
            if (OUT_BF) ((unsigned short*)xout)[off] = f2bf(v);
            else        ((float*)xout)[off] = v;
        }
    }
}

// ---------- fallback (int-atomic path, deterministic, f32) if ws too small ----------
__global__ void rpi_scatter_kernel(const float* __restrict__ x,
                                   const int* __restrict__ src,
                                   const int* __restrict__ dst,
                                   const float* __restrict__ ew,
                                   int* __restrict__ agg, int E) {
    int tid = blockIdx.x * blockDim.x + threadIdx.x;
    int e = tid >> 4;
    if (e >= E) return;
    int c = (tid & 15) << 2;
    int s = src[e], d = dst[e];
    float w = ew[e] * FP_SCALE;
    float4 v = *reinterpret_cast<const float4*>(&x[(size_t)s * D + c]);
    int* o = &agg[(size_t)d * D + c];
    atomicAdd(o + 0, (int)(w * v.x));
    atomicAdd(o + 1, (int)(w * v.y));
    atomicAdd(o + 2, (int)(w * v.z));
    atomicAdd(o + 3, (int)(w * v.w));
}

__global__ void rpi_linear_relu_kernel(const int* __restrict__ agg,
                                       const float* __restrict__ W,
                                       const float* __restrict__ b,
                                       float* __restrict__ out, int N) {
    __shared__ float Ws[D][D + 1];
    __shared__ float bs[D];
    int t = threadIdx.x;
    for (int i = t; i < D * D; i += 256) Ws[i >> 6][i & 63] = W[i];
    if (t < D) bs[t] = b[t];
    __syncthreads();
    int wave = t >> 6, lane = t & 63;
    int nwaves = gridDim.x * 4;
    for (int n = blockIdx.x * 4 + wave; n < N; n += nwaves) {
        const int* arow = &agg[(size_t)n * D];
        float acc = bs[lane];
        #pragma unroll
        for (int d = 0; d < D; ++d) acc = fmaf((float)arow[d] * FP_INV, Ws[lane][d], acc);
        out[(size_t)n * D + lane] = fmaxf(acc, 0.0f);
    }
}

extern "C" void kernel_launch(void* const* d_in, const int* in_sizes, int n_in,
                              void* d_out, int out_size, void* d_ws, size_t ws_size,
                              hipStream_t stream) {
    const float* x0 = (const float*)d_in[0];   // [N, 64]
    const int*   ei = (const int*)d_in[1];     // [2, E]
    const float* ew = (const float*)d_in[2];   // [E]
    const float* W  = (const float*)d_in[3];   // [64, 64]
    const float* b  = (const float*)d_in[4];   // [64]
    float* out = (float*)d_out;                // [N, 64]

    int N = in_sizes[0] / D;
    int E = in_sizes[2];
    const int* src = ei;
    const int* dst = ei + E;

    int nblk = (N + NPC - 1) / NPC;
    int npad = nblk * 16;                      // padded bucket count (4 nodes/bucket)
    int nb2  = (npad + 255) / 256;
    size_t xeb = (size_t)N * D * sizeof(unsigned short);   // 12.8 MB
    size_t off = 0;
    size_t o_xb1  = off; off += xeb;
    size_t o_xb2  = off; off += xeb;
    size_t o_p64  = off; off += (size_t)E * sizeof(unsigned long long);
    size_t o_cnt  = off; off += (size_t)npad * sizeof(int);
    size_t o_bs   = off; off += ((size_t)npad + 2) * sizeof(int);
    size_t o_cur  = off; off += (size_t)npad * sizeof(int);
    size_t o_part = off; off += ((size_t)nb2 + 16) * sizeof(int);
    size_t need = off;

    if (ws_size >= need) {
        unsigned short* xb1 = (unsigned short*)((char*)d_ws + o_xb1);
        unsigned short* xb2 = (unsigned short*)((char*)d_ws + o_xb2);
        unsigned long long* perm64 = (unsigned long long*)((char*)d_ws + o_p64);
        int* bktCnt      = (int*)((char*)d_ws + o_cnt);
        int* bucketStart = (int*)((char*)d_ws + o_bs);
        int* cursor      = (int*)((char*)d_ws + o_cur);
        int* partial     = (int*)((char*)d_ws + o_part);

        int eb = (E + 255) / 256;

        hipMemsetAsync(bktCnt, 0, (size_t)npad * sizeof(int), stream);
        hist_kernel  <<<eb, 256, 0, stream>>>(dst, bktCnt, E);
        part_kernel  <<<nb2, 256, 0, stream>>>(bktCnt, partial, npad);
        scan_kernel  <<<1, 512, 0, stream>>>(partial, nb2);
        bstart_kernel<<<nb2, 256, 0, stream>>>(bktCnt, partial, bucketStart, cursor, npad);
        fill_kernel  <<<eb, 256, 0, stream>>>(src, dst, ew, cursor, perm64, E);

        // iter 0 reads f32 x0 directly; iters ping-pong bf16
        agg_fused_kernel<true,  true> <<<nblk, 256, 0, stream>>>(x0,  perm64, bucketStart, W, b, xb2, N);
        agg_fused_kernel<false, true> <<<nblk, 256, 0, stream>>>(xb2, perm64, bucketStart, W, b, xb1, N);
        agg_fused_kernel<false, false><<<nblk, 256, 0, stream>>>(xb1, perm64, bucketStart, W, b, out, N);
    } else {
        int* agg = (int*)d_ws;
        const float* xcur = x0;
        int sb = (E * 16 + 255) / 256;
        for (int it = 0; it < 3; ++it) {
            hipMemsetAsync(agg, 0, (size_t)N * D * sizeof(int), stream);
            rpi_scatter_kernel<<<sb, 256, 0, stream>>>(xcur, src, dst, ew, agg, E);
            rpi_linear_relu_kernel<<<2048, 256, 0, stream>>>(agg, W, b, out, N);
            xcur = out;
        }
    }
}